// Round 19
// baseline (127.871 us; speedup 1.0000x reference)
//
#include <hip/hip_runtime.h>

using u16    = unsigned short;
using u32    = unsigned int;
using f32x4  = __attribute__((ext_vector_type(4))) float;
using f32x16 = __attribute__((ext_vector_type(16))) float;
using bf16x8 = __attribute__((ext_vector_type(8))) __bf16;
using u16x4  = __attribute__((ext_vector_type(4))) u16;
using u16x8  = __attribute__((ext_vector_type(8))) u16;
using u32x2  = __attribute__((ext_vector_type(2))) u32;
using u32x4  = __attribute__((ext_vector_type(4))) u32;
using i32x4  = __attribute__((ext_vector_type(4))) int;

// B=2, S=2048, D=1024, H=16, DK=64, M=B*S=4096.
// Softmax in exp2 domain with FIXED m=0 (normalization cancels exactly).
// KP/VP/MP packed layouts as R5-R18.
// attn R19: all 4 waves share ONE LDS-staged K/V tile (16KB, dbuf, counted
// vmcnt) -> block L2 traffic halves (1.07GB total -> ~0.5GB). Wave (qw,kh)
// reads its K-half + 2 V ks-slots from LDS. Split-K combine unchanged.
// gemm_qkv: R14 structure at (256,3) (R18; occupancy unchanged but harmless).

__device__ __forceinline__ u16 f2bf(float f) {
  union { __bf16 b; u16 u; } c; c.b = (__bf16)f; return c.u;
}

typedef __attribute__((address_space(1))) const void GVoid;
typedef __attribute__((address_space(3))) void LVoid;

__device__ __forceinline__ void gload_lds16(const void* g, void* l) {
  __builtin_amdgcn_global_load_lds((GVoid*)g, (LVoid*)l, 16, 0, 0);
}

// ---------------- fp32 -> bf16 conversion: WEIGHTS ONLY ----------------
__global__ void cvt_w(const float* __restrict__ a, const float* __restrict__ b,
                      const float* __restrict__ c, const float* __restrict__ dd,
                      u16* __restrict__ oa, u16* __restrict__ ob,
                      u16* __restrict__ oc, u16* __restrict__ od) {
  int y = blockIdx.y;
  const float* s = (y == 0) ? a : (y == 1) ? b : (y == 2) ? c : dd;
  u16* d = (y == 0) ? oa : (y == 1) ? ob : (y == 2) ? oc : od;
  int i = blockIdx.x * 256 + threadIdx.x;
  f32x4 v = ((const f32x4*)s)[i];
  u16x4 r;
#pragma unroll
  for (int j = 0; j < 4; ++j) r[j] = f2bf(v[j]);
  ((u16x4*)d)[i] = r;
}

// ---------------- mask bit-pack + transpose: [B,S,S] i32 -> MP[b][kt][q] u32x2 ----------------
__global__ void pack_mask(const int* __restrict__ m, u32* __restrict__ mp) {
  int tid = blockIdx.x * 256 + threadIdx.x;  // 131072 = 2*32*2048
  int q = tid & 2047, kt = (tid >> 11) & 31, b = tid >> 16;
  const i32x4* src = (const i32x4*)(m + ((size_t)(b * 2048 + q)) * 2048 + kt * 64);
  u32 w0 = 0, w1 = 0;
#pragma unroll
  for (int j = 0; j < 8; ++j) {
    i32x4 a = src[j], c = src[j + 8];
#pragma unroll
    for (int e = 0; e < 4; ++e) {
      w0 |= (a[e] != 0 ? 1u : 0u) << (j * 4 + e);
      w1 |= (c[e] != 0 ? 1u : 0u) << (j * 4 + e);
    }
  }
  ((u32x2*)mp)[((size_t)(b * 32 + kt)) * 2048 + q] = u32x2{w0, w1};
}

// ---------------- QKV GEMM (R14/R18): A fp32 via global_load_lds ----------------
__global__ __launch_bounds__(256, 3) void gemm_qkv(const float* __restrict__ Aq,
                                                   const float* __restrict__ Ak,
                                                   const float* __restrict__ Av,
                                                   const u16* __restrict__ Wb,
                                                   u16* __restrict__ out) {
  __shared__ alignas(16) char lds[49152];
  const int t = threadIdx.x;
  const int lane = t & 63, wid = t >> 6;
  const int g = lane >> 4, r16 = lane & 15;
  const int wm = wid >> 1, wn = wid & 1;
  const int m0 = blockIdx.x * 128, n0 = blockIdx.y * 128;
  const int z = blockIdx.z;

  const float* Axf = (z == 0) ? Aq : (z == 1) ? Ak : Av;
  const char* Ab = (const char*)Axf;
  const char* Bb = (const char*)(Wb + (size_t)z * 1048576);
  u16* op = out + (size_t)z * 4194304;
  const float qsc = (z == 0) ? 0.18033688011f : 1.0f;  // 0.125*log2(e) into Q

  f32x4 acc[4][4] = {};

  for (int kk = 0; kk < 1024; kk += 64) {
#pragma unroll
    for (int i = 0; i < 8; ++i) {
      int ci = i * 256 + t;          // 16B slot
      int row = ci >> 4;
      int pc = ci & 15;
      int lc = pc ^ (row & 15);
      gload_lds16(Ab + (size_t)(m0 + row) * 4096 + kk * 4 + lc * 16, lds + ci * 16);
    }
#pragma unroll
    for (int i = 0; i < 4; ++i) {
      int ci = i * 256 + t;
      int row = ci >> 3;
      int cbs = ((ci & 7) << 4) ^ ((row & 7) << 4);
      gload_lds16(Bb + (size_t)(n0 + row) * 2048 + kk * 2 + cbs, lds + 32768 + ci * 16);
    }
    __syncthreads();
#pragma unroll
    for (int kc = 0; kc < 2; ++kc) {
      bf16x8 af[4], bfr[4];
#pragma unroll
      for (int mf = 0; mf < 4; ++mf) {
        int row = wm * 64 + mf * 16 + r16;
        const char* arow = lds + row * 256;
        int x = row & 15;
        int lc0 = 8 * kc + 2 * g;    // logical 16B chunk of k = 32kc+8g
        f32x4 alo = *(const f32x4*)(arow + ((lc0 ^ x) * 16));
        f32x4 ahi = *(const f32x4*)(arow + (((lc0 + 1) ^ x) * 16));
        u16x8 pk;
#pragma unroll
        for (int j = 0; j < 4; ++j) { pk[j] = f2bf(alo[j]); pk[4 + j] = f2bf(ahi[j]); }
        af[mf] = __builtin_bit_cast(bf16x8, pk);
      }
#pragma unroll
      for (int nf = 0; nf < 4; ++nf) {
        int row = wn * 64 + nf * 16 + r16;
        bfr[nf] = *(const bf16x8*)(lds + 32768 + row * 128 +
                                   ((64 * kc + 16 * g) ^ ((row & 7) << 4)));
      }
#pragma unroll
      for (int mf = 0; mf < 4; ++mf)
#pragma unroll
        for (int nf = 0; nf < 4; ++nf)
          acc[mf][nf] = __builtin_amdgcn_mfma_f32_16x16x32_bf16(af[mf], bfr[nf], acc[mf][nf], 0, 0, 0);
    }
    __syncthreads();
  }

#pragma unroll
  for (int mf = 0; mf < 4; ++mf) {
#pragma unroll
    for (int nf = 0; nf < 4; ++nf) {
      int mb = m0 + wm * 64 + mf * 16 + 4 * g;
      int n = n0 + wn * 64 + nf * 16 + r16;
      if (z == 0) {  // Q: [B,H,S,DK] bf16, pre-scaled
        int bb = mb >> 11, h = n >> 6, dk = n & 63;
#pragma unroll
        for (int r = 0; r < 4; ++r) {
          int s2 = (mb + r) & 2047;
          op[((size_t)(bb * 16 + h) * 2048 + s2) * 64 + dk] = f2bf(acc[mf][nf][r] * qsc);
        }
      } else if (z == 1) {  // K packed: KP[bh][kt][half][chunk][l31] x16B
        int h = n >> 6, dk = n & 63;
#pragma unroll
        for (int r = 0; r < 4; ++r) {
          int m = mb + r;
          int bb = m >> 11, s2 = m & 2047;
          size_t off16 = ((((size_t)(bb * 16 + h) * 32 + (s2 >> 6)) * 2 + ((s2 >> 5) & 1)) * 8 +
                          (dk >> 3)) * 32 + (s2 & 31);
          op[off16 * 8 + (dk & 7)] = f2bf(acc[mf][nf][r]);
        }
      } else {  // V packed: VP[bh][kt][chunk][db][l31] x16B
        int bb = mb >> 11, s2 = mb & 2047, h = n >> 6, d = n & 63;
        size_t off16 = ((((size_t)(bb * 16 + h) * 32 + (s2 >> 6)) * 8 + ((s2 & 63) >> 3)) * 2 +
                        (d >> 5)) * 32 + (d & 31);
        u16x4 pv;
#pragma unroll
        for (int r = 0; r < 4; ++r) pv[r] = f2bf(acc[mf][nf][r]);
        *(u16x4*)(op + off16 * 8 + (s2 & 7)) = pv;
      }
    }
  }
}

// ---------------- out-projection GEMM: bf16 A (ctx), fp32 output ----------------
__global__ __launch_bounds__(256, 2) void gemm_out(const u16* __restrict__ X,
                                                   const u16* __restrict__ W,
                                                   float* __restrict__ out) {
  __shared__ alignas(16) char lds[32768];
  const int t = threadIdx.x;
  const int lane = t & 63, wid = t >> 6;
  const int g = lane >> 4, r16 = lane & 15;
  const int wm = wid >> 1, wn = wid & 1;
  const int m0 = blockIdx.x * 128, n0 = blockIdx.y * 128;
  const char* Ab = (const char*)X;
  const char* Bb = (const char*)W;

  f32x4 acc[4][4] = {};

  for (int kk = 0; kk < 1024; kk += 64) {
#pragma unroll
    for (int i = 0; i < 4; ++i) {
      int ci = i * 256 + t;
      int row = ci >> 3;
      int cbs = ((ci & 7) << 4) ^ ((row & 7) << 4);
      gload_lds16(Ab + (size_t)(m0 + row) * 2048 + kk * 2 + cbs, lds + ci * 16);
      gload_lds16(Bb + (size_t)(n0 + row) * 2048 + kk * 2 + cbs, lds + 16384 + ci * 16);
    }
    __syncthreads();
#pragma unroll
    for (int kc = 0; kc < 2; ++kc) {
      bf16x8 af[4], bfr[4];
#pragma unroll
      for (int mf = 0; mf < 4; ++mf) {
        int row = wm * 64 + mf * 16 + r16;
        af[mf] = *(const bf16x8*)(lds + row * 128 + ((64 * kc + 16 * g) ^ ((row & 7) << 4)));
      }
#pragma unroll
      for (int nf = 0; nf < 4; ++nf) {
        int row = wn * 64 + nf * 16 + r16;
        bfr[nf] = *(const bf16x8*)(lds + 16384 + row * 128 + ((64 * kc + 16 * g) ^ ((row & 7) << 4)));
      }
#pragma unroll
      for (int mf = 0; mf < 4; ++mf)
#pragma unroll
        for (int nf = 0; nf < 4; ++nf)
          acc[mf][nf] = __builtin_amdgcn_mfma_f32_16x16x32_bf16(af[mf], bfr[nf], acc[mf][nf], 0, 0, 0);
    }
    __syncthreads();
  }

#pragma unroll
  for (int mf = 0; mf < 4; ++mf)
#pragma unroll
    for (int nf = 0; nf < 4; ++nf) {
      int mb = m0 + wm * 64 + mf * 16 + 4 * g;
      int n = n0 + wn * 64 + nf * 16 + r16;
#pragma unroll
      for (int r = 0; r < 4; ++r) out[(size_t)(mb + r) * 1024 + n] = acc[mf][nf][r];
    }
}

// ---------------- flash attention: shared LDS K/V tile, split-K within tile ----------------
// 4 waves = {qsub qw} x {k-half kh}. Per tile (16KB staged once, dbuf'd):
// wave reads K-half kh (4 frags) + V ks-slots {2kh,2kh+1} (4 frags) from LDS.
__global__ __launch_bounds__(256, 2) void attn_kern(const u16* __restrict__ Qh,
                                                    const u16* __restrict__ Kh,
                                                    const u16* __restrict__ Vt,
                                                    const u32* __restrict__ mp,
                                                    u16* __restrict__ ctx) {
  __shared__ alignas(16) char lds[32768];  // dbuf 2 x (K 8KB | V 8KB); epilogue reuse as cmb
  const int t = threadIdx.x;
  const int wid = t >> 6, lane = t & 63;
  const int qw = wid & 1, kh = wid >> 1;
  const int hi = lane >> 5, l31 = lane & 31;

  // XCD-aware swizzle: 1024 blocks, 128-block chunk per XCD (bh-major within chunk)
  const int wg = (blockIdx.x & 7) * 128 + (blockIdx.x >> 3);
  const int qt = wg & 31, bh = wg >> 5;
  const int b = bh >> 4, h = bh & 15;

  const char* qbytes = (const char*)Qh;
  const int qbase = qt * 64 + qw * 32;
  const int qg = qbase + l31;

  // Q fragments (B operand): lane: q-col = l31, dk = 32c + 16hi + j (one-time)
  bf16x8 qf[4];
#pragma unroll
  for (int c = 0; c < 4; ++c)
    qf[c] = *(const bf16x8*)(qbytes + ((size_t)bh * 2048 + qg) * 128 + 32 * c + 16 * hi);

  const char* ktile = (const char*)Kh + (size_t)bh * 262144;  // + kt*8192
  const char* vtile = (const char*)Vt + (size_t)bh * 262144;  // + kt*8192
  const u32x2* mptr = (const u32x2*)mp + (size_t)b * 65536 + qg;

  f32x16 o0 = {}, o1 = {};  // o0: d = l31 (db0), o1: d = 32+l31 (db1)
  float l_run = 0.f;

#define STAGE(BUF, KT)                                                          \
  {                                                                             \
    _Pragma("unroll") for (int i = 0; i < 2; ++i) {                             \
      int ci = i * 256 + t;                                                     \
      gload_lds16(ktile + (size_t)(KT) * 8192 + ci * 16,                        \
                  lds + (BUF) * 16384 + ci * 16);                               \
      gload_lds16(vtile + (size_t)(KT) * 8192 + ci * 16,                        \
                  lds + (BUF) * 16384 + 8192 + ci * 16);                        \
    }                                                                           \
  }

  STAGE(0, 0);
  u32x2 mcur = *mptr;
  mptr += 2048;

#pragma unroll 1
  for (int kt = 0; kt < 32; ++kt) {
    const char* cb = lds + (kt & 1) * 16384;
    u32x2 mnext;
    if (kt < 31) {
      STAGE((kt + 1) & 1, kt + 1);
      mnext = *mptr;
      mptr += 2048;
      asm volatile("s_waitcnt vmcnt(5)" ::: "memory");  // cur's 4 staged done; next 4 + mask in flight
    } else {
      mnext = mcur;
      asm volatile("s_waitcnt vmcnt(0)" ::: "memory");
    }
    __builtin_amdgcn_s_barrier();
    asm volatile("" ::: "memory");

    // K fragments for this wave's half: K[k_rel = l31][dk = 32c + 16hi + j]
    bf16x8 kf[4];
#pragma unroll
    for (int c = 0; c < 4; ++c)
      kf[c] = *(const bf16x8*)(cb + kh * 4096 + c * 1024 + hi * 512 + l31 * 16);

    // QK^T: s[r] = S[k_rel = (r&3)+8(r>>2)+4hi][q = l31]
    f32x16 s = {};
#pragma unroll
    for (int c = 0; c < 4; ++c)
      s = __builtin_amdgcn_mfma_f32_32x32x16_bf16(kf[c], qf[c], s, 0, 0, 0);

    // p = 2^s, mask via sign-extend AND (word kh of packed mask)
    u32 wm = (kh ? mcur.y : mcur.x) >> (4 * hi);
    float ps = 0.f;
#pragma unroll
    for (int r = 0; r < 16; ++r) {
      const int bit = (r & 3) + 8 * (r >> 2);
      float p = __builtin_amdgcn_exp2f(s[r]);
      int sm = ((int)(wm << (31 - bit))) >> 31;
      p = __uint_as_float(__float_as_uint(p) & (u32)sm);
      s[r] = p;
      ps += p;
    }
    l_run += ps;

    // P -> bf16 A-fragments (8 cvt_pk + 4 permlane32_swap)
    u32 w[8];
#pragma unroll
    for (int ss = 0; ss < 2; ++ss) {
      u32 A0, B0, A1, B1;
      asm("v_cvt_pk_bf16_f32 %0, %1, %2" : "=v"(A0) : "v"(s[8*ss+0]), "v"(s[8*ss+1]));
      asm("v_cvt_pk_bf16_f32 %0, %1, %2" : "=v"(B0) : "v"(s[8*ss+2]), "v"(s[8*ss+3]));
      asm("v_cvt_pk_bf16_f32 %0, %1, %2" : "=v"(A1) : "v"(s[8*ss+4]), "v"(s[8*ss+5]));
      asm("v_cvt_pk_bf16_f32 %0, %1, %2" : "=v"(B1) : "v"(s[8*ss+6]), "v"(s[8*ss+7]));
      asm("v_permlane32_swap_b32 %0, %1" : "+v"(A0), "+v"(A1));
      asm("v_permlane32_swap_b32 %0, %1" : "+v"(B0), "+v"(B1));
      w[4*ss+0] = A0; w[4*ss+1] = B0; w[4*ss+2] = A1; w[4*ss+3] = B1;
    }

    // V fragments (ks_abs = 2kh+ss): chunk = 2*ks_abs + hi, db = output half
    // PV: o[db] += pa(ss) x V(ss, db)
#pragma unroll
    for (int ss = 0; ss < 2; ++ss) {
      bf16x8 pa = __builtin_bit_cast(bf16x8, u32x4{w[4*ss], w[4*ss+1], w[4*ss+2], w[4*ss+3]});
      const char* vbase = cb + 8192 + (size_t)(4 * kh + 2 * ss + hi) * 1024 + l31 * 16;
      bf16x8 v0 = *(const bf16x8*)(vbase);
      bf16x8 v1 = *(const bf16x8*)(vbase + 512);
      o0 = __builtin_amdgcn_mfma_f32_32x32x16_bf16(pa, v0, o0, 0, 0, 0);
      o1 = __builtin_amdgcn_mfma_f32_32x32x16_bf16(pa, v1, o1, 0, 0, 0);
    }

    asm volatile("" ::: "memory");
    __builtin_amdgcn_s_barrier();  // all reads of cb done before it is restaged
    asm volatile("" ::: "memory");
    mcur = mnext;
  }
#undef STAGE

  // ---- split-K combine (LDS reused as cmb; all staging drained, loop barriers passed)
  __syncthreads();
  float* cmb  = (float*)lds;            // [2][32][64] = 16 KB
  float* cmbl = (float*)(lds + 16384);  // [2][64]

  l_run += __shfl_xor(l_run, 32, 64);

  if (kh) {
#pragma unroll
    for (int r = 0; r < 16; ++r) {
      cmb[(qw * 32 + r) * 64 + lane]      = o0[r];
      cmb[(qw * 32 + 16 + r) * 64 + lane] = o1[r];
    }
    cmbl[qw * 64 + lane] = l_run;
  }
  __syncthreads();
  if (!kh) {
#pragma unroll
    for (int r = 0; r < 16; ++r) {
      o0[r] += cmb[(qw * 32 + r) * 64 + lane];
      o1[r] += cmb[(qw * 32 + 16 + r) * 64 + lane];
    }
    l_run += cmbl[qw * 64 + lane];

    float rl = 1.f / l_run;
#pragma unroll
    for (int r = 0; r < 16; ++r) {
      float rv = __shfl(rl, (r & 3) + 8 * (r >> 2) + 4 * hi, 64);
      int q = qbase + (r & 3) + 8 * (r >> 2) + 4 * hi;
      size_t rowp = ((size_t)b * 2048 + q) * 1024 + h * 64 + l31;
      ctx[rowp]      = f2bf(o0[r] * rv);
      ctx[rowp + 32] = f2bf(o1[r] * rv);
    }
  }
}

// ---------------- launch ----------------
extern "C" void kernel_launch(void* const* d_in, const int* in_sizes, int n_in,
                              void* d_out, int out_size, void* d_ws, size_t ws_size,
                              hipStream_t stream) {
  const float* q  = (const float*)d_in[0];
  const float* k  = (const float*)d_in[1];
  const float* v  = (const float*)d_in[2];
  const int* mask = (const int*)d_in[3];
  const float* Wq = (const float*)d_in[4];
  const float* Wk = (const float*)d_in[5];
  const float* Wv = (const float*)d_in[6];
  const float* Wo = (const float*)d_in[7];

  u16* ws = (u16*)d_ws;
  const size_t NX = (size_t)4096 * 1024;
  const size_t NW = (size_t)1024 * 1024;
  u16* Wqb = ws + 3 * NX;
  u16* Qh  = Wqb + 4 * NW;          // Qh | KP | VP consecutive
  u16* ctx = Qh + 3 * NX;
  u32* mpk = (u32*)ws;              // 1 MB

  cvt_w<<<dim3(1024, 4), 256, 0, stream>>>(Wq, Wk, Wv, Wo,
                                           Wqb, Wqb + NW, Wqb + 2 * NW, Wqb + 3 * NW);
  pack_mask<<<dim3(512), 256, 0, stream>>>(mask, mpk);
  gemm_qkv<<<dim3(32, 8, 3), 256, 0, stream>>>(q, k, v, Wqb, Qh);
  attn_kern<<<dim3(1024), 256, 0, stream>>>(Qh, Qh + NX, Qh + 2 * NX, mpk, ctx);
  gemm_out<<<dim3(32, 8), 256, 0, stream>>>(ctx, Wqb + 3 * NW, (float*)d_out);
}

// Round 20
// 126.061 us; speedup vs baseline: 1.0144x; 1.0144x over previous
//
#include <hip/hip_runtime.h>

using u16    = unsigned short;
using u32    = unsigned int;
using f32x4  = __attribute__((ext_vector_type(4))) float;
using f32x16 = __attribute__((ext_vector_type(16))) float;
using bf16x8 = __attribute__((ext_vector_type(8))) __bf16;
using u16x4  = __attribute__((ext_vector_type(4))) u16;
using u16x8  = __attribute__((ext_vector_type(8))) u16;
using u32x2  = __attribute__((ext_vector_type(2))) u32;
using u32x4  = __attribute__((ext_vector_type(4))) u32;
using i32x4  = __attribute__((ext_vector_type(4))) int;

// B=2, S=2048, D=1024, H=16, DK=64, M=B*S=4096.
// Softmax in exp2 domain with FIXED m=0 (normalization cancels exactly).
// KP/VP/MP packed layouts as R5-R19.
// attn R20: lean per-wave split (qw x kh, R19) + ZERO-BARRIER global-direct
// fragment loads (R5) + reg-dbuf K (R9) -> unified demand ~144 fits (256,3).
// gemm_qkv: R14 structure at (256,3) (R18).

__device__ __forceinline__ u16 f2bf(float f) {
  union { __bf16 b; u16 u; } c; c.b = (__bf16)f; return c.u;
}

typedef __attribute__((address_space(1))) const void GVoid;
typedef __attribute__((address_space(3))) void LVoid;

__device__ __forceinline__ void gload_lds16(const void* g, void* l) {
  __builtin_amdgcn_global_load_lds((GVoid*)g, (LVoid*)l, 16, 0, 0);
}

// ---------------- fp32 -> bf16 conversion: WEIGHTS ONLY ----------------
__global__ void cvt_w(const float* __restrict__ a, const float* __restrict__ b,
                      const float* __restrict__ c, const float* __restrict__ dd,
                      u16* __restrict__ oa, u16* __restrict__ ob,
                      u16* __restrict__ oc, u16* __restrict__ od) {
  int y = blockIdx.y;
  const float* s = (y == 0) ? a : (y == 1) ? b : (y == 2) ? c : dd;
  u16* d = (y == 0) ? oa : (y == 1) ? ob : (y == 2) ? oc : od;
  int i = blockIdx.x * 256 + threadIdx.x;
  f32x4 v = ((const f32x4*)s)[i];
  u16x4 r;
#pragma unroll
  for (int j = 0; j < 4; ++j) r[j] = f2bf(v[j]);
  ((u16x4*)d)[i] = r;
}

// ---------------- mask bit-pack + transpose: [B,S,S] i32 -> MP[b][kt][q] u32x2 ----------------
__global__ void pack_mask(const int* __restrict__ m, u32* __restrict__ mp) {
  int tid = blockIdx.x * 256 + threadIdx.x;  // 131072 = 2*32*2048
  int q = tid & 2047, kt = (tid >> 11) & 31, b = tid >> 16;
  const i32x4* src = (const i32x4*)(m + ((size_t)(b * 2048 + q)) * 2048 + kt * 64);
  u32 w0 = 0, w1 = 0;
#pragma unroll
  for (int j = 0; j < 8; ++j) {
    i32x4 a = src[j], c = src[j + 8];
#pragma unroll
    for (int e = 0; e < 4; ++e) {
      w0 |= (a[e] != 0 ? 1u : 0u) << (j * 4 + e);
      w1 |= (c[e] != 0 ? 1u : 0u) << (j * 4 + e);
    }
  }
  ((u32x2*)mp)[((size_t)(b * 32 + kt)) * 2048 + q] = u32x2{w0, w1};
}

// ---------------- QKV GEMM (R14/R18): A fp32 via global_load_lds ----------------
__global__ __launch_bounds__(256, 3) void gemm_qkv(const float* __restrict__ Aq,
                                                   const float* __restrict__ Ak,
                                                   const float* __restrict__ Av,
                                                   const u16* __restrict__ Wb,
                                                   u16* __restrict__ out) {
  __shared__ alignas(16) char lds[49152];
  const int t = threadIdx.x;
  const int lane = t & 63, wid = t >> 6;
  const int g = lane >> 4, r16 = lane & 15;
  const int wm = wid >> 1, wn = wid & 1;
  const int m0 = blockIdx.x * 128, n0 = blockIdx.y * 128;
  const int z = blockIdx.z;

  const float* Axf = (z == 0) ? Aq : (z == 1) ? Ak : Av;
  const char* Ab = (const char*)Axf;
  const char* Bb = (const char*)(Wb + (size_t)z * 1048576);
  u16* op = out + (size_t)z * 4194304;
  const float qsc = (z == 0) ? 0.18033688011f : 1.0f;  // 0.125*log2(e) into Q

  f32x4 acc[4][4] = {};

  for (int kk = 0; kk < 1024; kk += 64) {
#pragma unroll
    for (int i = 0; i < 8; ++i) {
      int ci = i * 256 + t;          // 16B slot
      int row = ci >> 4;
      int pc = ci & 15;
      int lc = pc ^ (row & 15);
      gload_lds16(Ab + (size_t)(m0 + row) * 4096 + kk * 4 + lc * 16, lds + ci * 16);
    }
#pragma unroll
    for (int i = 0; i < 4; ++i) {
      int ci = i * 256 + t;
      int row = ci >> 3;
      int cbs = ((ci & 7) << 4) ^ ((row & 7) << 4);
      gload_lds16(Bb + (size_t)(n0 + row) * 2048 + kk * 2 + cbs, lds + 32768 + ci * 16);
    }
    __syncthreads();
#pragma unroll
    for (int kc = 0; kc < 2; ++kc) {
      bf16x8 af[4], bfr[4];
#pragma unroll
      for (int mf = 0; mf < 4; ++mf) {
        int row = wm * 64 + mf * 16 + r16;
        const char* arow = lds + row * 256;
        int x = row & 15;
        int lc0 = 8 * kc + 2 * g;    // logical 16B chunk of k = 32kc+8g
        f32x4 alo = *(const f32x4*)(arow + ((lc0 ^ x) * 16));
        f32x4 ahi = *(const f32x4*)(arow + (((lc0 + 1) ^ x) * 16));
        u16x8 pk;
#pragma unroll
        for (int j = 0; j < 4; ++j) { pk[j] = f2bf(alo[j]); pk[4 + j] = f2bf(ahi[j]); }
        af[mf] = __builtin_bit_cast(bf16x8, pk);
      }
#pragma unroll
      for (int nf = 0; nf < 4; ++nf) {
        int row = wn * 64 + nf * 16 + r16;
        bfr[nf] = *(const bf16x8*)(lds + 32768 + row * 128 +
                                   ((64 * kc + 16 * g) ^ ((row & 7) << 4)));
      }
#pragma unroll
      for (int mf = 0; mf < 4; ++mf)
#pragma unroll
        for (int nf = 0; nf < 4; ++nf)
          acc[mf][nf] = __builtin_amdgcn_mfma_f32_16x16x32_bf16(af[mf], bfr[nf], acc[mf][nf], 0, 0, 0);
    }
    __syncthreads();
  }

#pragma unroll
  for (int mf = 0; mf < 4; ++mf) {
#pragma unroll
    for (int nf = 0; nf < 4; ++nf) {
      int mb = m0 + wm * 64 + mf * 16 + 4 * g;
      int n = n0 + wn * 64 + nf * 16 + r16;
      if (z == 0) {  // Q: [B,H,S,DK] bf16, pre-scaled
        int bb = mb >> 11, h = n >> 6, dk = n & 63;
#pragma unroll
        for (int r = 0; r < 4; ++r) {
          int s2 = (mb + r) & 2047;
          op[((size_t)(bb * 16 + h) * 2048 + s2) * 64 + dk] = f2bf(acc[mf][nf][r] * qsc);
        }
      } else if (z == 1) {  // K packed: KP[bh][kt][half][chunk][l31] x16B
        int h = n >> 6, dk = n & 63;
#pragma unroll
        for (int r = 0; r < 4; ++r) {
          int m = mb + r;
          int bb = m >> 11, s2 = m & 2047;
          size_t off16 = ((((size_t)(bb * 16 + h) * 32 + (s2 >> 6)) * 2 + ((s2 >> 5) & 1)) * 8 +
                          (dk >> 3)) * 32 + (s2 & 31);
          op[off16 * 8 + (dk & 7)] = f2bf(acc[mf][nf][r]);
        }
      } else {  // V packed: VP[bh][kt][chunk][db][l31] x16B
        int bb = mb >> 11, s2 = mb & 2047, h = n >> 6, d = n & 63;
        size_t off16 = ((((size_t)(bb * 16 + h) * 32 + (s2 >> 6)) * 8 + ((s2 & 63) >> 3)) * 2 +
                        (d >> 5)) * 32 + (d & 31);
        u16x4 pv;
#pragma unroll
        for (int r = 0; r < 4; ++r) pv[r] = f2bf(acc[mf][nf][r]);
        *(u16x4*)(op + off16 * 8 + (s2 & 7)) = pv;
      }
    }
  }
}

// ---------------- out-projection GEMM: bf16 A (ctx), fp32 output ----------------
__global__ __launch_bounds__(256, 2) void gemm_out(const u16* __restrict__ X,
                                                   const u16* __restrict__ W,
                                                   float* __restrict__ out) {
  __shared__ alignas(16) char lds[32768];
  const int t = threadIdx.x;
  const int lane = t & 63, wid = t >> 6;
  const int g = lane >> 4, r16 = lane & 15;
  const int wm = wid >> 1, wn = wid & 1;
  const int m0 = blockIdx.x * 128, n0 = blockIdx.y * 128;
  const char* Ab = (const char*)X;
  const char* Bb = (const char*)W;

  f32x4 acc[4][4] = {};

  for (int kk = 0; kk < 1024; kk += 64) {
#pragma unroll
    for (int i = 0; i < 4; ++i) {
      int ci = i * 256 + t;
      int row = ci >> 3;
      int cbs = ((ci & 7) << 4) ^ ((row & 7) << 4);
      gload_lds16(Ab + (size_t)(m0 + row) * 2048 + kk * 2 + cbs, lds + ci * 16);
      gload_lds16(Bb + (size_t)(n0 + row) * 2048 + kk * 2 + cbs, lds + 16384 + ci * 16);
    }
    __syncthreads();
#pragma unroll
    for (int kc = 0; kc < 2; ++kc) {
      bf16x8 af[4], bfr[4];
#pragma unroll
      for (int mf = 0; mf < 4; ++mf) {
        int row = wm * 64 + mf * 16 + r16;
        af[mf] = *(const bf16x8*)(lds + row * 128 + ((64 * kc + 16 * g) ^ ((row & 7) << 4)));
      }
#pragma unroll
      for (int nf = 0; nf < 4; ++nf) {
        int row = wn * 64 + nf * 16 + r16;
        bfr[nf] = *(const bf16x8*)(lds + 16384 + row * 128 + ((64 * kc + 16 * g) ^ ((row & 7) << 4)));
      }
#pragma unroll
      for (int mf = 0; mf < 4; ++mf)
#pragma unroll
        for (int nf = 0; nf < 4; ++nf)
          acc[mf][nf] = __builtin_amdgcn_mfma_f32_16x16x32_bf16(af[mf], bfr[nf], acc[mf][nf], 0, 0, 0);
    }
    __syncthreads();
  }

#pragma unroll
  for (int mf = 0; mf < 4; ++mf)
#pragma unroll
    for (int nf = 0; nf < 4; ++nf) {
      int mb = m0 + wm * 64 + mf * 16 + 4 * g;
      int n = n0 + wn * 64 + nf * 16 + r16;
#pragma unroll
      for (int r = 0; r < 4; ++r) out[(size_t)(mb + r) * 1024 + n] = acc[mf][nf][r];
    }
}

// ---------------- flash attention: lean split, global-direct, ZERO barriers ----------------
// 4 waves = {qsub qw} x {k-half kh}; each wave: 32 q x 32 k-rows of every tile,
// both d-halves. Fragments straight from packed KP/VP (dense 1KB/512B segments,
// L2-resident). K reg-double-buffered; no inter-wave sync until combine.
struct KH { bf16x8 k[4]; };

__device__ __forceinline__ void loadKh(KH& f, const char* p) {
#pragma unroll
  for (int c = 0; c < 4; ++c) f.k[c] = *(const bf16x8*)(p + c * 1024);
}

__device__ __forceinline__ void attn_body(const bf16x8 (&qf)[4], KH& cur, KH& nxt,
                                          const char*& kp, const char*& vp,
                                          const u32x2*& mptr, u32x2& mcur,
                                          int kh, int hi,
                                          f32x16& o0, f32x16& o1, float& l_run) {
  // V for CURRENT tile: [ss][db] (consumed at PV; L2 latency hidden in-iter)
  bf16x8 v00 = *(const bf16x8*)(vp);
  bf16x8 v01 = *(const bf16x8*)(vp + 512);
  bf16x8 v10 = *(const bf16x8*)(vp + 2048);
  bf16x8 v11 = *(const bf16x8*)(vp + 2560);
  // K + mask for NEXT tile (explicit dbuf)
  loadKh(nxt, kp);
  u32x2 mnext = *mptr;
  kp += 8192; vp += 8192; mptr += 2048;
  __builtin_amdgcn_sched_barrier(0);  // pin load issue above compute

  // QK^T: s[r] = S[k_rel = (r&3)+8(r>>2)+4hi][q = l31]
  f32x16 s = {};
#pragma unroll
  for (int c = 0; c < 4; ++c)
    s = __builtin_amdgcn_mfma_f32_32x32x16_bf16(cur.k[c], qf[c], s, 0, 0, 0);

  // p = 2^s, mask via sign-extend AND (word kh of packed mask pair)
  u32 wm = (kh ? mcur.y : mcur.x) >> (4 * hi);
  float ps = 0.f;
#pragma unroll
  for (int r = 0; r < 16; ++r) {
    const int bit = (r & 3) + 8 * (r >> 2);
    float p = __builtin_amdgcn_exp2f(s[r]);
    int sm = ((int)(wm << (31 - bit))) >> 31;
    p = __uint_as_float(__float_as_uint(p) & (u32)sm);
    s[r] = p;
    ps += p;
  }
  l_run += ps;

  // P -> bf16 A-fragments (8 cvt_pk + 4 permlane32_swap)
  u32 w[8];
#pragma unroll
  for (int ss = 0; ss < 2; ++ss) {
    u32 A0, B0, A1, B1;
    asm("v_cvt_pk_bf16_f32 %0, %1, %2" : "=v"(A0) : "v"(s[8*ss+0]), "v"(s[8*ss+1]));
    asm("v_cvt_pk_bf16_f32 %0, %1, %2" : "=v"(B0) : "v"(s[8*ss+2]), "v"(s[8*ss+3]));
    asm("v_cvt_pk_bf16_f32 %0, %1, %2" : "=v"(A1) : "v"(s[8*ss+4]), "v"(s[8*ss+5]));
    asm("v_cvt_pk_bf16_f32 %0, %1, %2" : "=v"(B1) : "v"(s[8*ss+6]), "v"(s[8*ss+7]));
    asm("v_permlane32_swap_b32 %0, %1" : "+v"(A0), "+v"(A1));
    asm("v_permlane32_swap_b32 %0, %1" : "+v"(B0), "+v"(B1));
    w[4*ss+0] = A0; w[4*ss+1] = B0; w[4*ss+2] = A1; w[4*ss+3] = B1;
  }

  // PV: o[db] += pa(ss) x V(ss, db)
  bf16x8 pa0 = __builtin_bit_cast(bf16x8, u32x4{w[0], w[1], w[2], w[3]});
  bf16x8 pa1 = __builtin_bit_cast(bf16x8, u32x4{w[4], w[5], w[6], w[7]});
  o0 = __builtin_amdgcn_mfma_f32_32x32x16_bf16(pa0, v00, o0, 0, 0, 0);
  o1 = __builtin_amdgcn_mfma_f32_32x32x16_bf16(pa0, v01, o1, 0, 0, 0);
  o0 = __builtin_amdgcn_mfma_f32_32x32x16_bf16(pa1, v10, o0, 0, 0, 0);
  o1 = __builtin_amdgcn_mfma_f32_32x32x16_bf16(pa1, v11, o1, 0, 0, 0);
  mcur = mnext;
}

__global__ __launch_bounds__(256, 3) void attn_kern(const u16* __restrict__ Qh,
                                                    const u16* __restrict__ Kh,
                                                    const u16* __restrict__ Vt,
                                                    const u32* __restrict__ mp,
                                                    u16* __restrict__ ctx) {
  __shared__ float cmb[2][32][64];   // 16 KB: kh=1 partial O per q-subtile
  __shared__ float cmbl[2][64];      // 512 B
  const int t = threadIdx.x;
  const int wid = t >> 6, lane = t & 63;
  const int qw = wid & 1, kh = wid >> 1;
  const int hi = lane >> 5, l31 = lane & 31;

  // XCD-aware swizzle: 1024 blocks, 128-block chunk per XCD
  const int wg = (blockIdx.x & 7) * 128 + (blockIdx.x >> 3);
  const int qt = wg & 31, bh = wg >> 5;
  const int b = bh >> 4, h = bh & 15;

  const char* qbytes = (const char*)Qh;
  const int qbase = qt * 64 + qw * 32;
  const int qg = qbase + l31;

  // Q fragments (B operand): lane: q-col = l31, dk = 32c + 16hi + j (one-time)
  bf16x8 qf[4];
#pragma unroll
  for (int c = 0; c < 4; ++c)
    qf[c] = *(const bf16x8*)(qbytes + ((size_t)bh * 2048 + qg) * 128 + 32 * c + 16 * hi);

  // per-lane packed pointers (dense coalesced segments)
  const char* kp = (const char*)Kh + (size_t)bh * 262144 + kh * 4096 + hi * 512 + l31 * 16;
  const char* vp = (const char*)Vt + (size_t)bh * 262144 + (size_t)(4 * kh + hi) * 1024 + l31 * 16;
  const u32x2* mptr = (const u32x2*)mp + (size_t)b * 65536 + qg;

  f32x16 o0 = {}, o1 = {};
  float l_run = 0.f;

  KH A, B2;
  loadKh(A, kp);
  kp += 8192;
  u32x2 mcur = *mptr;
  mptr += 2048;

#pragma unroll 1
  for (int it = 0; it < 16; ++it) {   // 32 tiles, 2 bodies/iter
    attn_body(qf, A, B2, kp, vp, mptr, mcur, kh, hi, o0, o1, l_run);
    attn_body(qf, B2, A, kp, vp, mptr, mcur, kh, hi, o0, o1, l_run);
  }

  // per-wave row-sum (lane + partner ^32 cover this wave's 32 k per tile)
  l_run += __shfl_xor(l_run, 32, 64);

  // split-K combine: waves kh=1 publish partials, kh=0 add + store
  if (kh) {
#pragma unroll
    for (int r = 0; r < 16; ++r) {
      cmb[qw][r][lane]      = o0[r];
      cmb[qw][16 + r][lane] = o1[r];
    }
    cmbl[qw][lane] = l_run;
  }
  __syncthreads();
  if (!kh) {
#pragma unroll
    for (int r = 0; r < 16; ++r) {
      o0[r] += cmb[qw][r][lane];
      o1[r] += cmb[qw][16 + r][lane];
    }
    l_run += cmbl[qw][lane];

    float rl = 1.f / l_run;
#pragma unroll
    for (int r = 0; r < 16; ++r) {
      float rv = __shfl(rl, (r & 3) + 8 * (r >> 2) + 4 * hi, 64);
      int q = qbase + (r & 3) + 8 * (r >> 2) + 4 * hi;
      size_t rowp = ((size_t)b * 2048 + q) * 1024 + h * 64 + l31;
      ctx[rowp]      = f2bf(o0[r] * rv);
      ctx[rowp + 32] = f2bf(o1[r] * rv);
    }
  }
}

// ---------------- launch ----------------
extern "C" void kernel_launch(void* const* d_in, const int* in_sizes, int n_in,
                              void* d_out, int out_size, void* d_ws, size_t ws_size,
                              hipStream_t stream) {
  const float* q  = (const float*)d_in[0];
  const float* k  = (const float*)d_in[1];
  const float* v  = (const float*)d_in[2];
  const int* mask = (const int*)d_in[3];
  const float* Wq = (const float*)d_in[4];
  const float* Wk = (const float*)d_in[5];
  const float* Wv = (const float*)d_in[6];
  const float* Wo = (const float*)d_in[7];

  u16* ws = (u16*)d_ws;
  const size_t NX = (size_t)4096 * 1024;
  const size_t NW = (size_t)1024 * 1024;
  u16* Wqb = ws + 3 * NX;
  u16* Qh  = Wqb + 4 * NW;          // Qh | KP | VP consecutive
  u16* ctx = Qh + 3 * NX;
  u32* mpk = (u32*)ws;              // 1 MB

  cvt_w<<<dim3(1024, 4), 256, 0, stream>>>(Wq, Wk, Wv, Wo,
                                           Wqb, Wqb + NW, Wqb + 2 * NW, Wqb + 3 * NW);
  pack_mask<<<dim3(512), 256, 0, stream>>>(mask, mpk);
  gemm_qkv<<<dim3(32, 8, 3), 256, 0, stream>>>(q, k, v, Wqb, Qh);
  attn_kern<<<dim3(1024), 256, 0, stream>>>(Qh, Qh + NX, Qh + 2 * NX, mpk, ctx);
  gemm_out<<<dim3(32, 8), 256, 0, stream>>>(ctx, Wqb + 3 * NW, (float*)d_out);
}

// Round 21
// 121.896 us; speedup vs baseline: 1.0490x; 1.0342x over previous
//
#include <hip/hip_runtime.h>

using u16    = unsigned short;
using u32    = unsigned int;
using f32x4  = __attribute__((ext_vector_type(4))) float;
using f32x16 = __attribute__((ext_vector_type(16))) float;
using bf16x8 = __attribute__((ext_vector_type(8))) __bf16;
using u16x4  = __attribute__((ext_vector_type(4))) u16;
using u16x8  = __attribute__((ext_vector_type(8))) u16;
using u32x2  = __attribute__((ext_vector_type(2))) u32;
using u32x4  = __attribute__((ext_vector_type(4))) u32;
using i32x4  = __attribute__((ext_vector_type(4))) int;

// B=2, S=2048, D=1024, H=16, DK=64, M=B*S=4096.
// Softmax in exp2 domain with FIXED m=0 (normalization cancels exactly).
// KP/VP/MP packed layouts as R5-R20.
// attn R21: TWO independent q-streams per wave (64 q-rows) -> doubled intra-wave
// ILP on the serial QK->exp2->cvt->PV chain; K and V fragments reused x2.
// Zero-barrier global-direct loads (R20), (256,2) proven-clean cap.
// gemm_qkv: R14 structure at (256,3) (R18).

__device__ __forceinline__ u16 f2bf(float f) {
  union { __bf16 b; u16 u; } c; c.b = (__bf16)f; return c.u;
}

typedef __attribute__((address_space(1))) const void GVoid;
typedef __attribute__((address_space(3))) void LVoid;

__device__ __forceinline__ void gload_lds16(const void* g, void* l) {
  __builtin_amdgcn_global_load_lds((GVoid*)g, (LVoid*)l, 16, 0, 0);
}

// ---------------- fp32 -> bf16 conversion: WEIGHTS ONLY ----------------
__global__ void cvt_w(const float* __restrict__ a, const float* __restrict__ b,
                      const float* __restrict__ c, const float* __restrict__ dd,
                      u16* __restrict__ oa, u16* __restrict__ ob,
                      u16* __restrict__ oc, u16* __restrict__ od) {
  int y = blockIdx.y;
  const float* s = (y == 0) ? a : (y == 1) ? b : (y == 2) ? c : dd;
  u16* d = (y == 0) ? oa : (y == 1) ? ob : (y == 2) ? oc : od;
  int i = blockIdx.x * 256 + threadIdx.x;
  f32x4 v = ((const f32x4*)s)[i];
  u16x4 r;
#pragma unroll
  for (int j = 0; j < 4; ++j) r[j] = f2bf(v[j]);
  ((u16x4*)d)[i] = r;
}

// ---------------- mask bit-pack + transpose: [B,S,S] i32 -> MP[b][kt][q] u32x2 ----------------
__global__ void pack_mask(const int* __restrict__ m, u32* __restrict__ mp) {
  int tid = blockIdx.x * 256 + threadIdx.x;  // 131072 = 2*32*2048
  int q = tid & 2047, kt = (tid >> 11) & 31, b = tid >> 16;
  const i32x4* src = (const i32x4*)(m + ((size_t)(b * 2048 + q)) * 2048 + kt * 64);
  u32 w0 = 0, w1 = 0;
#pragma unroll
  for (int j = 0; j < 8; ++j) {
    i32x4 a = src[j], c = src[j + 8];
#pragma unroll
    for (int e = 0; e < 4; ++e) {
      w0 |= (a[e] != 0 ? 1u : 0u) << (j * 4 + e);
      w1 |= (c[e] != 0 ? 1u : 0u) << (j * 4 + e);
    }
  }
  ((u32x2*)mp)[((size_t)(b * 32 + kt)) * 2048 + q] = u32x2{w0, w1};
}

// ---------------- QKV GEMM (R14/R18): A fp32 via global_load_lds ----------------
__global__ __launch_bounds__(256, 3) void gemm_qkv(const float* __restrict__ Aq,
                                                   const float* __restrict__ Ak,
                                                   const float* __restrict__ Av,
                                                   const u16* __restrict__ Wb,
                                                   u16* __restrict__ out) {
  __shared__ alignas(16) char lds[49152];
  const int t = threadIdx.x;
  const int lane = t & 63, wid = t >> 6;
  const int g = lane >> 4, r16 = lane & 15;
  const int wm = wid >> 1, wn = wid & 1;
  const int m0 = blockIdx.x * 128, n0 = blockIdx.y * 128;
  const int z = blockIdx.z;

  const float* Axf = (z == 0) ? Aq : (z == 1) ? Ak : Av;
  const char* Ab = (const char*)Axf;
  const char* Bb = (const char*)(Wb + (size_t)z * 1048576);
  u16* op = out + (size_t)z * 4194304;
  const float qsc = (z == 0) ? 0.18033688011f : 1.0f;  // 0.125*log2(e) into Q

  f32x4 acc[4][4] = {};

  for (int kk = 0; kk < 1024; kk += 64) {
#pragma unroll
    for (int i = 0; i < 8; ++i) {
      int ci = i * 256 + t;          // 16B slot
      int row = ci >> 4;
      int pc = ci & 15;
      int lc = pc ^ (row & 15);
      gload_lds16(Ab + (size_t)(m0 + row) * 4096 + kk * 4 + lc * 16, lds + ci * 16);
    }
#pragma unroll
    for (int i = 0; i < 4; ++i) {
      int ci = i * 256 + t;
      int row = ci >> 3;
      int cbs = ((ci & 7) << 4) ^ ((row & 7) << 4);
      gload_lds16(Bb + (size_t)(n0 + row) * 2048 + kk * 2 + cbs, lds + 32768 + ci * 16);
    }
    __syncthreads();
#pragma unroll
    for (int kc = 0; kc < 2; ++kc) {
      bf16x8 af[4], bfr[4];
#pragma unroll
      for (int mf = 0; mf < 4; ++mf) {
        int row = wm * 64 + mf * 16 + r16;
        const char* arow = lds + row * 256;
        int x = row & 15;
        int lc0 = 8 * kc + 2 * g;    // logical 16B chunk of k = 32kc+8g
        f32x4 alo = *(const f32x4*)(arow + ((lc0 ^ x) * 16));
        f32x4 ahi = *(const f32x4*)(arow + (((lc0 + 1) ^ x) * 16));
        u16x8 pk;
#pragma unroll
        for (int j = 0; j < 4; ++j) { pk[j] = f2bf(alo[j]); pk[4 + j] = f2bf(ahi[j]); }
        af[mf] = __builtin_bit_cast(bf16x8, pk);
      }
#pragma unroll
      for (int nf = 0; nf < 4; ++nf) {
        int row = wn * 64 + nf * 16 + r16;
        bfr[nf] = *(const bf16x8*)(lds + 32768 + row * 128 +
                                   ((64 * kc + 16 * g) ^ ((row & 7) << 4)));
      }
#pragma unroll
      for (int mf = 0; mf < 4; ++mf)
#pragma unroll
        for (int nf = 0; nf < 4; ++nf)
          acc[mf][nf] = __builtin_amdgcn_mfma_f32_16x16x32_bf16(af[mf], bfr[nf], acc[mf][nf], 0, 0, 0);
    }
    __syncthreads();
  }

#pragma unroll
  for (int mf = 0; mf < 4; ++mf) {
#pragma unroll
    for (int nf = 0; nf < 4; ++nf) {
      int mb = m0 + wm * 64 + mf * 16 + 4 * g;
      int n = n0 + wn * 64 + nf * 16 + r16;
      if (z == 0) {  // Q: [B,H,S,DK] bf16, pre-scaled
        int bb = mb >> 11, h = n >> 6, dk = n & 63;
#pragma unroll
        for (int r = 0; r < 4; ++r) {
          int s2 = (mb + r) & 2047;
          op[((size_t)(bb * 16 + h) * 2048 + s2) * 64 + dk] = f2bf(acc[mf][nf][r] * qsc);
        }
      } else if (z == 1) {  // K packed: KP[bh][kt][half][chunk][l31] x16B
        int h = n >> 6, dk = n & 63;
#pragma unroll
        for (int r = 0; r < 4; ++r) {
          int m = mb + r;
          int bb = m >> 11, s2 = m & 2047;
          size_t off16 = ((((size_t)(bb * 16 + h) * 32 + (s2 >> 6)) * 2 + ((s2 >> 5) & 1)) * 8 +
                          (dk >> 3)) * 32 + (s2 & 31);
          op[off16 * 8 + (dk & 7)] = f2bf(acc[mf][nf][r]);
        }
      } else {  // V packed: VP[bh][kt][chunk][db][l31] x16B
        int bb = mb >> 11, s2 = mb & 2047, h = n >> 6, d = n & 63;
        size_t off16 = ((((size_t)(bb * 16 + h) * 32 + (s2 >> 6)) * 8 + ((s2 & 63) >> 3)) * 2 +
                        (d >> 5)) * 32 + (d & 31);
        u16x4 pv;
#pragma unroll
        for (int r = 0; r < 4; ++r) pv[r] = f2bf(acc[mf][nf][r]);
        *(u16x4*)(op + off16 * 8 + (s2 & 7)) = pv;
      }
    }
  }
}

// ---------------- out-projection GEMM: bf16 A (ctx), fp32 output ----------------
__global__ __launch_bounds__(256, 2) void gemm_out(const u16* __restrict__ X,
                                                   const u16* __restrict__ W,
                                                   float* __restrict__ out) {
  __shared__ alignas(16) char lds[32768];
  const int t = threadIdx.x;
  const int lane = t & 63, wid = t >> 6;
  const int g = lane >> 4, r16 = lane & 15;
  const int wm = wid >> 1, wn = wid & 1;
  const int m0 = blockIdx.x * 128, n0 = blockIdx.y * 128;
  const char* Ab = (const char*)X;
  const char* Bb = (const char*)W;

  f32x4 acc[4][4] = {};

  for (int kk = 0; kk < 1024; kk += 64) {
#pragma unroll
    for (int i = 0; i < 4; ++i) {
      int ci = i * 256 + t;
      int row = ci >> 3;
      int cbs = ((ci & 7) << 4) ^ ((row & 7) << 4);
      gload_lds16(Ab + (size_t)(m0 + row) * 2048 + kk * 2 + cbs, lds + ci * 16);
      gload_lds16(Bb + (size_t)(n0 + row) * 2048 + kk * 2 + cbs, lds + 16384 + ci * 16);
    }
    __syncthreads();
#pragma unroll
    for (int kc = 0; kc < 2; ++kc) {
      bf16x8 af[4], bfr[4];
#pragma unroll
      for (int mf = 0; mf < 4; ++mf) {
        int row = wm * 64 + mf * 16 + r16;
        af[mf] = *(const bf16x8*)(lds + row * 128 + ((64 * kc + 16 * g) ^ ((row & 7) << 4)));
      }
#pragma unroll
      for (int nf = 0; nf < 4; ++nf) {
        int row = wn * 64 + nf * 16 + r16;
        bfr[nf] = *(const bf16x8*)(lds + 16384 + row * 128 + ((64 * kc + 16 * g) ^ ((row & 7) << 4)));
      }
#pragma unroll
      for (int mf = 0; mf < 4; ++mf)
#pragma unroll
        for (int nf = 0; nf < 4; ++nf)
          acc[mf][nf] = __builtin_amdgcn_mfma_f32_16x16x32_bf16(af[mf], bfr[nf], acc[mf][nf], 0, 0, 0);
    }
    __syncthreads();
  }

#pragma unroll
  for (int mf = 0; mf < 4; ++mf)
#pragma unroll
    for (int nf = 0; nf < 4; ++nf) {
      int mb = m0 + wm * 64 + mf * 16 + 4 * g;
      int n = n0 + wn * 64 + nf * 16 + r16;
#pragma unroll
      for (int r = 0; r < 4; ++r) out[(size_t)(mb + r) * 1024 + n] = acc[mf][nf][r];
    }
}

// ---------------- flash attention: 2 q-streams/wave, zero-barrier, (256,2) ----------------
// 4 waves = {qw} x {kh}; wave owns q rows [qw*64, qw*64+64) as streams a/b
// (32 rows each) and k-half kh of every tile. K/V fragments shared by streams.
struct KH { bf16x8 k[4]; };

__device__ __forceinline__ void loadKh(KH& f, const char* p) {
#pragma unroll
  for (int c = 0; c < 4; ++c) f.k[c] = *(const bf16x8*)(p + c * 1024);
}

// one stream's softmax+cvt: s (QK out) -> masked p, partial sum, bf16 frags
__device__ __forceinline__ void sm_cvt(f32x16& s, u32 wm, float& lr, u32 (&w)[8]) {
  float ps = 0.f;
#pragma unroll
  for (int r = 0; r < 16; ++r) {
    const int bit = (r & 3) + 8 * (r >> 2);
    float p = __builtin_amdgcn_exp2f(s[r]);
    int sm = ((int)(wm << (31 - bit))) >> 31;
    p = __uint_as_float(__float_as_uint(p) & (u32)sm);
    s[r] = p;
    ps += p;
  }
  lr += ps;
#pragma unroll
  for (int ss = 0; ss < 2; ++ss) {
    u32 A0, B0, A1, B1;
    asm("v_cvt_pk_bf16_f32 %0, %1, %2" : "=v"(A0) : "v"(s[8*ss+0]), "v"(s[8*ss+1]));
    asm("v_cvt_pk_bf16_f32 %0, %1, %2" : "=v"(B0) : "v"(s[8*ss+2]), "v"(s[8*ss+3]));
    asm("v_cvt_pk_bf16_f32 %0, %1, %2" : "=v"(A1) : "v"(s[8*ss+4]), "v"(s[8*ss+5]));
    asm("v_cvt_pk_bf16_f32 %0, %1, %2" : "=v"(B1) : "v"(s[8*ss+6]), "v"(s[8*ss+7]));
    asm("v_permlane32_swap_b32 %0, %1" : "+v"(A0), "+v"(A1));
    asm("v_permlane32_swap_b32 %0, %1" : "+v"(B0), "+v"(B1));
    w[4*ss+0] = A0; w[4*ss+1] = B0; w[4*ss+2] = A1; w[4*ss+3] = B1;
  }
}

__device__ __forceinline__ void attn_body(const bf16x8 (&qfa)[4], const bf16x8 (&qfb)[4],
                                          KH& cur, KH& nxt,
                                          const char*& kp, const char*& vp,
                                          const u32x2*& mpa, const u32x2*& mpb,
                                          u32x2& mca, u32x2& mcb,
                                          int kh, int hi,
                                          f32x16& oa0, f32x16& oa1,
                                          f32x16& ob0, f32x16& ob1,
                                          float& lra, float& lrb) {
  // V for CURRENT tile (shared by both q-streams)
  bf16x8 v00 = *(const bf16x8*)(vp);
  bf16x8 v01 = *(const bf16x8*)(vp + 512);
  bf16x8 v10 = *(const bf16x8*)(vp + 2048);
  bf16x8 v11 = *(const bf16x8*)(vp + 2560);
  // K + masks for NEXT tile (explicit dbuf)
  loadKh(nxt, kp);
  u32x2 mna = *mpa;
  u32x2 mnb = *mpb;
  kp += 8192; vp += 8192; mpa += 2048; mpb += 2048;
  __builtin_amdgcn_sched_barrier(0);  // pin load issue above compute

  // QK^T: two independent chains
  f32x16 sa = {}, sb = {};
#pragma unroll
  for (int c = 0; c < 4; ++c) {
    sa = __builtin_amdgcn_mfma_f32_32x32x16_bf16(cur.k[c], qfa[c], sa, 0, 0, 0);
    sb = __builtin_amdgcn_mfma_f32_32x32x16_bf16(cur.k[c], qfb[c], sb, 0, 0, 0);
  }

  u32 wma = (kh ? mca.y : mca.x) >> (4 * hi);
  u32 wmb = (kh ? mcb.y : mcb.x) >> (4 * hi);
  u32 wa[8], wb[8];
  sm_cvt(sa, wma, lra, wa);
  sm_cvt(sb, wmb, lrb, wb);

  // PV: both streams consume the same V fragments
  bf16x8 pa0 = __builtin_bit_cast(bf16x8, u32x4{wa[0], wa[1], wa[2], wa[3]});
  bf16x8 pa1 = __builtin_bit_cast(bf16x8, u32x4{wa[4], wa[5], wa[6], wa[7]});
  bf16x8 pb0 = __builtin_bit_cast(bf16x8, u32x4{wb[0], wb[1], wb[2], wb[3]});
  bf16x8 pb1 = __builtin_bit_cast(bf16x8, u32x4{wb[4], wb[5], wb[6], wb[7]});
  oa0 = __builtin_amdgcn_mfma_f32_32x32x16_bf16(pa0, v00, oa0, 0, 0, 0);
  ob0 = __builtin_amdgcn_mfma_f32_32x32x16_bf16(pb0, v00, ob0, 0, 0, 0);
  oa1 = __builtin_amdgcn_mfma_f32_32x32x16_bf16(pa0, v01, oa1, 0, 0, 0);
  ob1 = __builtin_amdgcn_mfma_f32_32x32x16_bf16(pb0, v01, ob1, 0, 0, 0);
  oa0 = __builtin_amdgcn_mfma_f32_32x32x16_bf16(pa1, v10, oa0, 0, 0, 0);
  ob0 = __builtin_amdgcn_mfma_f32_32x32x16_bf16(pb1, v10, ob0, 0, 0, 0);
  oa1 = __builtin_amdgcn_mfma_f32_32x32x16_bf16(pa1, v11, oa1, 0, 0, 0);
  ob1 = __builtin_amdgcn_mfma_f32_32x32x16_bf16(pb1, v11, ob1, 0, 0, 0);
  mca = mna;
  mcb = mnb;
}

__global__ __launch_bounds__(256, 2) void attn_kern(const u16* __restrict__ Qh,
                                                    const u16* __restrict__ Kh,
                                                    const u16* __restrict__ Vt,
                                                    const u32* __restrict__ mp,
                                                    u16* __restrict__ ctx) {
  __shared__ float cmb[2][2][32][64];  // 32 KB: kh=1 partials per (qw, stream)
  __shared__ float cmbl[2][2][64];     // 1 KB
  const int t = threadIdx.x;
  const int wid = t >> 6, lane = t & 63;
  const int qw = wid & 1, kh = wid >> 1;
  const int hi = lane >> 5, l31 = lane & 31;

  // XCD-aware swizzle: 512 blocks, 64-block chunk per XCD
  const int wg = (blockIdx.x & 7) * 64 + (blockIdx.x >> 3);
  const int qt = wg & 15, bh = wg >> 4;
  const int b = bh >> 4, h = bh & 15;

  const char* qbytes = (const char*)Qh;
  const int qbase_a = qt * 128 + qw * 64;        // stream a: 32 rows
  const int qbase_b = qbase_a + 32;              // stream b: next 32 rows
  const int qga = qbase_a + l31;
  const int qgb = qbase_b + l31;

  bf16x8 qfa[4], qfb[4];
#pragma unroll
  for (int c = 0; c < 4; ++c) {
    qfa[c] = *(const bf16x8*)(qbytes + ((size_t)bh * 2048 + qga) * 128 + 32 * c + 16 * hi);
    qfb[c] = *(const bf16x8*)(qbytes + ((size_t)bh * 2048 + qgb) * 128 + 32 * c + 16 * hi);
  }

  const char* kp = (const char*)Kh + (size_t)bh * 262144 + kh * 4096 + hi * 512 + l31 * 16;
  const char* vp = (const char*)Vt + (size_t)bh * 262144 + (size_t)(4 * kh + hi) * 1024 + l31 * 16;
  const u32x2* mpa = (const u32x2*)mp + (size_t)b * 65536 + qga;
  const u32x2* mpb = (const u32x2*)mp + (size_t)b * 65536 + qgb;

  f32x16 oa0 = {}, oa1 = {}, ob0 = {}, ob1 = {};
  float lra = 0.f, lrb = 0.f;

  KH A, B2;
  loadKh(A, kp);
  kp += 8192;
  u32x2 mca = *mpa;
  u32x2 mcb = *mpb;
  mpa += 2048; mpb += 2048;

#pragma unroll 1
  for (int it = 0; it < 16; ++it) {   // 32 tiles, 2 bodies/iter
    attn_body(qfa, qfb, A, B2, kp, vp, mpa, mpb, mca, mcb, kh, hi, oa0, oa1, ob0, ob1, lra, lrb);
    attn_body(qfa, qfb, B2, A, kp, vp, mpa, mpb, mca, mcb, kh, hi, oa0, oa1, ob0, ob1, lra, lrb);
  }

  lra += __shfl_xor(lra, 32, 64);
  lrb += __shfl_xor(lrb, 32, 64);

  // split-K combine: kh=1 publishes, kh=0 adds + stores (both streams)
  if (kh) {
#pragma unroll
    for (int r = 0; r < 16; ++r) {
      cmb[qw][0][r][lane]      = oa0[r];
      cmb[qw][0][16 + r][lane] = oa1[r];
      cmb[qw][1][r][lane]      = ob0[r];
      cmb[qw][1][16 + r][lane] = ob1[r];
    }
    cmbl[qw][0][lane] = lra;
    cmbl[qw][1][lane] = lrb;
  }
  __syncthreads();
  if (!kh) {
#pragma unroll
    for (int r = 0; r < 16; ++r) {
      oa0[r] += cmb[qw][0][r][lane];
      oa1[r] += cmb[qw][0][16 + r][lane];
      ob0[r] += cmb[qw][1][r][lane];
      ob1[r] += cmb[qw][1][16 + r][lane];
    }
    lra += cmbl[qw][0][lane];
    lrb += cmbl[qw][1][lane];

    float rla = 1.f / lra, rlb = 1.f / lrb;
#pragma unroll
    for (int r = 0; r < 16; ++r) {
      int crow = (r & 3) + 8 * (r >> 2) + 4 * hi;
      float rva = __shfl(rla, crow, 64);
      float rvb = __shfl(rlb, crow, 64);
      size_t rowa = ((size_t)b * 2048 + qbase_a + crow) * 1024 + h * 64 + l31;
      size_t rowb = ((size_t)b * 2048 + qbase_b + crow) * 1024 + h * 64 + l31;
      ctx[rowa]      = f2bf(oa0[r] * rva);
      ctx[rowa + 32] = f2bf(oa1[r] * rva);
      ctx[rowb]      = f2bf(ob0[r] * rvb);
      ctx[rowb + 32] = f2bf(ob1[r] * rvb);
    }
  }
}

// ---------------- launch ----------------
extern "C" void kernel_launch(void* const* d_in, const int* in_sizes, int n_in,
                              void* d_out, int out_size, void* d_ws, size_t ws_size,
                              hipStream_t stream) {
  const float* q  = (const float*)d_in[0];
  const float* k  = (const float*)d_in[1];
  const float* v  = (const float*)d_in[2];
  const int* mask = (const int*)d_in[3];
  const float* Wq = (const float*)d_in[4];
  const float* Wk = (const float*)d_in[5];
  const float* Wv = (const float*)d_in[6];
  const float* Wo = (const float*)d_in[7];

  u16* ws = (u16*)d_ws;
  const size_t NX = (size_t)4096 * 1024;
  const size_t NW = (size_t)1024 * 1024;
  u16* Wqb = ws + 3 * NX;
  u16* Qh  = Wqb + 4 * NW;          // Qh | KP | VP consecutive
  u16* ctx = Qh + 3 * NX;
  u32* mpk = (u32*)ws;              // 1 MB

  cvt_w<<<dim3(1024, 4), 256, 0, stream>>>(Wq, Wk, Wv, Wo,
                                           Wqb, Wqb + NW, Wqb + 2 * NW, Wqb + 3 * NW);
  pack_mask<<<dim3(512), 256, 0, stream>>>(mask, mpk);
  gemm_qkv<<<dim3(32, 8, 3), 256, 0, stream>>>(q, k, v, Wqb, Qh);
  attn_kern<<<dim3(512), 256, 0, stream>>>(Qh, Qh + NX, Qh + 2 * NX, mpk, ctx);
  gemm_out<<<dim3(32, 8), 256, 0, stream>>>(ctx, Wqb + 3 * NW, (float*)d_out);
}